// Round 3
// baseline (347.193 us; speedup 1.0000x reference)
//
#include <hip/hip_runtime.h>

// conv_transpose2d(x(4,256,128,128), w(256,256,4,4) block-diagonal, stride=2)
// -> out (4,256,258,258). Depthwise: off-diagonal w entries are exactly 0.0,
// so using only w[c][c] is bit-identical to the dense conv.
//
// R5 design: R4's dense-store structure (lane j owns output cols 4j..4j+3 of
// a full row; one wave store = contiguous 1024 B) plus:
//   - NONTEMPORAL stores for all output: out is written once and never read;
//     273 MB of dirty lines through L2/L3 is pure overhead (no reuse: working
//     set 340 MB > 256 MiB L3).
//   - Nontemporal loads for x (each input row consumed ~once).
//   - Unroll 2 row-pairs per trip with 2-row-deep prefetch: doubles the
//     independent memory ops in flight per wave.
// Filter w[c][c] loaded with uniform indices -> SGPRs; no LDS, no syncs.

#define CCH   256
#define HIN   128
#define WIN   128
#define HOUT  258
#define WOUT  258
#define PAIRS 129            // cell-rows ci in [0,128]; out rows 2ci, 2ci+1
#define PERB  17             // row-pairs per band (8 bands: 7x17 + 1x10)

typedef float v4f __attribute__((ext_vector_type(4)));
typedef float v2f __attribute__((ext_vector_type(2)));

struct RowT { float m, a, b; };   // cols {2j-1, 2j, 2j+1} of one input row

__device__ __forceinline__ RowT load_row(const float* __restrict__ xs,
                                         int r, int lane, bool en) {
    RowT t;
    if (en) {                     // wave-uniform condition
        const v2f v = __builtin_nontemporal_load(
            reinterpret_cast<const v2f*>(xs + (size_t)r * WIN + 2 * lane));
        t.a = v.x; t.b = v.y;
        t.m = __shfl_up(t.b, 1);
        if (lane == 0) t.m = 0.f;
    } else {
        t.m = 0.f; t.a = 0.f; t.b = 0.f;
    }
    return t;
}

// P = x[ci-1], Q = x[ci]; writes out rows 2ci (at pr) and 2ci+1 (at pr+WOUT).
__device__ __forceinline__ void store_pair(const RowT P, const RowT Q,
                                           const float* __restrict__ f,
                                           float* __restrict__ pr, int lane) {
    v4f r;
    r.x = Q.a*f[0] + Q.m*f[2] + P.a*f[8]  + P.m*f[10];
    r.y = Q.a*f[1] + Q.m*f[3] + P.a*f[9]  + P.m*f[11];
    r.z = Q.b*f[0] + Q.a*f[2] + P.b*f[8]  + P.a*f[10];
    r.w = Q.b*f[1] + Q.a*f[3] + P.b*f[9]  + P.a*f[11];
    __builtin_nontemporal_store(r, reinterpret_cast<v4f*>(pr));
    if (lane == 63) {             // cols 256,257: cj=128, only m-terms
        v2f t; t.x = Q.b*f[2] + P.b*f[10];
               t.y = Q.b*f[3] + P.b*f[11];
        __builtin_nontemporal_store(t, reinterpret_cast<v2f*>(pr + 4));
    }
    r.x = Q.a*f[4] + Q.m*f[6] + P.a*f[12] + P.m*f[14];
    r.y = Q.a*f[5] + Q.m*f[7] + P.a*f[13] + P.m*f[15];
    r.z = Q.b*f[4] + Q.a*f[6] + P.b*f[12] + P.a*f[14];
    r.w = Q.b*f[5] + Q.a*f[7] + P.b*f[13] + P.a*f[15];
    __builtin_nontemporal_store(r, reinterpret_cast<v4f*>(pr + WOUT));
    if (lane == 63) {
        v2f t; t.x = Q.b*f[6] + P.b*f[14];
               t.y = Q.b*f[7] + P.b*f[15];
        __builtin_nontemporal_store(t, reinterpret_cast<v2f*>(pr + WOUT + 4));
    }
}

__global__ __launch_bounds__(256) void upconv2x_kernel(
    const float* __restrict__ x,
    const float* __restrict__ w,
    float* __restrict__ out)
{
    const int slice = blockIdx.y;             // n*CCH + c
    const int c = slice & (CCH - 1);

    // Uniform index -> scalar loads into SGPRs (no LDS, no sync)
    const float* __restrict__ wf = w + ((size_t)c * CCH + c) * 16;
    float f[16];
#pragma unroll
    for (int i = 0; i < 16; ++i) f[i] = wf[i];

    const int wave = threadIdx.x >> 6;
    const int lane = threadIdx.x & 63;
    const int band = (blockIdx.x << 2) + wave;     // 0..7
    const int c0 = band * PERB;
    const int c1 = (c0 + PERB < PAIRS) ? (c0 + PERB) : PAIRS;

    const float* __restrict__ xs = x + (size_t)slice * (HIN * WIN);

    // Software pipeline: hold rows x[ci-1], x[ci], x[ci+1]; prefetch 2/trip.
    RowT A = load_row(xs, c0 - 1, lane, c0 > 0);       // x[c0-1]
    RowT B = load_row(xs, c0,     lane, true);         // x[c0]   (c0 <= 119)
    RowT C = load_row(xs, c0 + 1, lane, c0 + 1 < HIN); // x[c0+1]

    float* __restrict__ pr = out + (size_t)slice * ((size_t)HOUT * WOUT)
                           + (size_t)(2 * c0) * WOUT + 4 * lane;

    for (int ci = c0; ci < c1; ci += 2) {
        // prefetch rows ci+2, ci+3 (wave-uniform guards; zeros past x end)
        RowT D = load_row(xs, ci + 2, lane, (ci + 2 < c1) && (ci + 2 < HIN));
        RowT E = load_row(xs, ci + 3, lane, (ci + 3 < c1) && (ci + 3 < HIN));

        store_pair(A, B, f, pr, lane);                       // pair ci
        if (ci + 1 < c1)                                     // pair ci+1
            store_pair(B, C, f, pr + 2 * WOUT, lane);

        A = C; B = D; C = E;
        pr += 4 * WOUT;
    }
}

extern "C" void kernel_launch(void* const* d_in, const int* in_sizes, int n_in,
                              void* d_out, int out_size, void* d_ws, size_t ws_size,
                              hipStream_t stream) {
    const float* x = (const float*)d_in[0];
    const float* w = (const float*)d_in[1];
    float* out = (float*)d_out;

    dim3 block(256);                 // 4 waves = bands 4b..4b+3 of one slice
    dim3 grid(2, 4 * CCH);           // 2 half-slices x 1024 slices
    upconv2x_kernel<<<grid, block, 0, stream>>>(x, w, out);
}

// Round 4
// 340.700 us; speedup vs baseline: 1.0191x; 1.0191x over previous
//
#include <hip/hip_runtime.h>

// conv_transpose2d(x(4,256,128,128), w(256,256,4,4) block-diagonal, stride=2)
// -> out (4,256,258,258). Depthwise: off-diagonal w entries are exactly 0.0,
// so using only w[c][c] is bit-identical to the dense conv.
//
// R6 = DIAGNOSTIC round. Same per-wave code as R4 (dense 1024B wave stores,
// registers+shfl halo, filter in SGPRs, normal cached stores), but grid.x
// halved: each wave serially processes TWO bands (band = wave, wave+4).
// Purpose: push the kernel's dispatch duration (~165us, invisible below the
// rocprof top-5 cutoff of ~170us) to ~330us so its FETCH_SIZE / WRITE_SIZE /
// VALUBusy / Occupancy counters finally become visible. This intentionally
// costs ~160us e2e THIS ROUND; the grid split reverts next round once the
// counters identify the 3x-off-roofline cause.

#define CCH   256
#define HIN   128
#define WIN   128
#define HOUT  258
#define WOUT  258
#define PAIRS 129            // cell-rows ci in [0,128]; out rows 2ci, 2ci+1
#define PERB  17             // row-pairs per band (8 bands: 7x17 + 1x10)

__global__ __launch_bounds__(256) void upconv2x_kernel(
    const float* __restrict__ x,
    const float* __restrict__ w,
    float* __restrict__ out)
{
    const int slice = blockIdx.y;             // n*CCH + c
    const int c = slice & (CCH - 1);

    // Uniform index -> scalar loads into SGPRs (no LDS, no sync)
    const float* __restrict__ wf = w + ((size_t)c * CCH + c) * 16;
    float f[16];
#pragma unroll
    for (int i = 0; i < 16; ++i) f[i] = wf[i];

    const int wave = threadIdx.x >> 6;
    const int lane = threadIdx.x & 63;

    const float* __restrict__ xs = x + (size_t)slice * (HIN * WIN);
    float* __restrict__ os = out + (size_t)slice * ((size_t)HOUT * WOUT);

    for (int half = 0; half < 2; ++half) {
        const int band = half * 4 + wave;          // 0..7
        const int c0 = band * PERB;
        const int c1 = (c0 + PERB < PAIRS) ? (c0 + PERB) : PAIRS;

        // Registers for input rows at cols {2j-1, 2j, 2j+1}:
        //   p* = x[ci-1], c* = x[ci]
        float pm = 0.f, p0v = 0.f, p1v = 0.f;
        float cm = 0.f, c0v = 0.f, c1v = 0.f;
        if (c0 > 0) {                              // wave-uniform branch
            const float2 v = *(const float2*)(xs + (size_t)(c0 - 1) * WIN + 2 * lane);
            p0v = v.x; p1v = v.y;
            pm = __shfl_up(p1v, 1); if (lane == 0) pm = 0.f;
        }
        {   // c0 <= 119 < HIN always
            const float2 v = *(const float2*)(xs + (size_t)c0 * WIN + 2 * lane);
            c0v = v.x; c1v = v.y;
            cm = __shfl_up(c1v, 1); if (lane == 0) cm = 0.f;
        }

        float* __restrict__ pr = os + (size_t)(2 * c0) * WOUT + 4 * lane;

        for (int ci = c0; ci < c1; ++ci) {
            // prefetch next input row (wave-uniform condition)
            float nm = 0.f, n0v = 0.f, n1v = 0.f;
            if ((ci + 1 < c1) && (ci + 1 < HIN)) {
                const float2 v = *(const float2*)(xs + (size_t)(ci + 1) * WIN + 2 * lane);
                n0v = v.x; n1v = v.y;
                nm = __shfl_up(n1v, 1); if (lane == 0) nm = 0.f;
            }

            // out[2ci][2cj+dw] = x[ci][cj]*f[dw] + x[ci][cj-1]*f[dw+2]
            //                  + x[ci-1][cj]*f[8+dw] + x[ci-1][cj-1]*f[10+dw]
            // lane j covers cj = 2j (cols 4j,4j+1) and cj = 2j+1 (cols 4j+2,4j+3)
            float4 r;
            r.x = c0v*f[0] + cm *f[2] + p0v*f[8]  + pm *f[10];
            r.y = c0v*f[1] + cm *f[3] + p0v*f[9]  + pm *f[11];
            r.z = c1v*f[0] + c0v*f[2] + p1v*f[8]  + p0v*f[10];
            r.w = c1v*f[1] + c0v*f[3] + p1v*f[9]  + p0v*f[11];
            *(float4*)pr = r;                        // dense 1024 B per wave
            if (lane == 63)                          // cols 256,257: cj=128, m-terms only
                *(float2*)(pr + 4) = make_float2(c1v*f[2] + p1v*f[10],
                                                 c1v*f[3] + p1v*f[11]);

            r.x = c0v*f[4] + cm *f[6] + p0v*f[12] + pm *f[14];
            r.y = c0v*f[5] + cm *f[7] + p0v*f[13] + pm *f[15];
            r.z = c1v*f[4] + c0v*f[6] + p1v*f[12] + p0v*f[14];
            r.w = c1v*f[5] + c0v*f[7] + p1v*f[13] + p0v*f[15];
            *(float4*)(pr + WOUT) = r;
            if (lane == 63)
                *(float2*)(pr + WOUT + 4) = make_float2(c1v*f[6] + p1v*f[14],
                                                        c1v*f[7] + p1v*f[15]);

            // rotate rows: prev <- cur <- next
            pm = cm; p0v = c0v; p1v = c1v;
            cm = nm; c0v = n0v; c1v = n1v;
            pr += 2 * WOUT;
        }
    }
}

extern "C" void kernel_launch(void* const* d_in, const int* in_sizes, int n_in,
                              void* d_out, int out_size, void* d_ws, size_t ws_size,
                              hipStream_t stream) {
    const float* x = (const float*)d_in[0];
    const float* w = (const float*)d_in[1];
    float* out = (float*)d_out;

    dim3 block(256);                 // 4 waves; each does 2 bands serially
    dim3 grid(1, 4 * CCH);           // 1024 blocks -> ~330us dispatch, visible in top-5
    upconv2x_kernel<<<grid, block, 0, stream>>>(x, w, out);
}